// Round 20
// baseline (105.356 us; speedup 1.0000x reference)
//
#include <hip/hip_runtime.h>
#include <cstdint>
#include <cstddef>

// ---------------------------------------------------------------------------
// MHA forward: x[2,2048,1024] fp32, wqkv[3072,1024], wo[1024,1024], wo_b[1024]
// out = concat(y[2,2048,1024], k[2,16,2048,64], v[2,16,2048,64]) fp32
// Pipeline: cvt->bf16 (fused); QKV GEMM (r15: 128x192, 2-phase, vmcnt(3));
// flash causal attn (NEW: QBLK=128, 512 thr / 8 waves = wh-quarter x wk-half,
// staging per unit work halved, wave count preserved); proj GEMM (r19 2-phase).
// ---------------------------------------------------------------------------

using bf16x8 = __attribute__((ext_vector_type(8))) __bf16;
using f32x4  = __attribute__((ext_vector_type(4))) float;
using u16    = unsigned short;

#define SOFT_SCALE 0.1803368801111244f   // 0.125 * log2(e)  (attn in exp2 domain)

// fp32 -> bf16 bits, round-to-nearest-even
__device__ __forceinline__ u16 f2bf(float f) {
  union { float f; uint32_t u; } a; a.f = f;
  uint32_t r = a.u + 0x7fffu + ((a.u >> 16) & 1u);
  return (u16)(r >> 16);
}

__device__ __forceinline__ bf16x8 ldfrag(const u16* p) {
  return *reinterpret_cast<const bf16x8*>(p);
}

__device__ __forceinline__ void gload_lds16(const void* g, void* l) {
  __builtin_amdgcn_global_load_lds((const __attribute__((address_space(1))) void*)g,
                                   (__attribute__((address_space(3))) void*)l,
                                   16, 0, 0);
}

// pack two fp32 -> one u32 of two bf16 (lo = a, hi = b), RNE
__device__ __forceinline__ uint32_t cvt_pk_bf16(float a, float b) {
  uint32_t r;
  asm("v_cvt_pk_bf16_f32 %0, %1, %2" : "=v"(r) : "v"(a), "v"(b));
  return r;
}

// ---------------------------------------------------------------------------
// fused fp32 -> bf16 convert for x, wqkv, wo (single launch)
// ---------------------------------------------------------------------------
__global__ void cvt_all(const float* __restrict__ x, const float* __restrict__ wqkv,
                        const float* __restrict__ wo,
                        u16* __restrict__ xb, u16* __restrict__ wqkvb, u16* __restrict__ wob) {
  int i = blockIdx.x * blockDim.x + threadIdx.x;
  int stride = gridDim.x * blockDim.x;
  for (; i < 2097152; i += stride) {
    const float* src; u16* dst; int j;
    if (i < 1048576)      { src = x;    dst = xb;    j = i; }
    else if (i < 1835008) { src = wqkv; dst = wqkvb; j = i - 1048576; }
    else                  { src = wo;   dst = wob;   j = i - 1835008; }
    float4 v = reinterpret_cast<const float4*>(src)[j];
    ushort4 o;
    o.x = f2bf(v.x); o.y = f2bf(v.y); o.z = f2bf(v.z); o.w = f2bf(v.w);
    reinterpret_cast<ushort4*>(dst)[j] = o;
  }
}

// ---------------------------------------------------------------------------
// QKV GEMM (r15, validated): 128x192 tiles, grid 512 = 2/CU, 80KB LDS,
// 2-phase fine interleave, counted vmcnt(3), Q pre-scaled.
// ---------------------------------------------------------------------------
__global__ __launch_bounds__(512, 2) void qkv_gemm_kernel(
    const u16* __restrict__ Xb, const u16* __restrict__ Wb,
    u16* __restrict__ Qws, u16* __restrict__ Kws, u16* __restrict__ Vtws,
    float* __restrict__ out) {
  extern __shared__ char smem[];

  const int tid = threadIdx.x, lane = tid & 63, wid = tid >> 6;
  const int wr = wid >> 2, wc = wid & 3;
  const int fq = lane >> 4, fr = lane & 15;

  const int wg = (blockIdx.x & 7) * 64 + (blockIdx.x >> 3);
  const int bm = wg >> 4, bn = wg & 15;
  const int m0 = bm * 128, n0 = bn * 192;

  const char* Ab = (const char*)Xb + (size_t)m0 * 2048;
  const char* Bb = (const char*)Wb + (size_t)n0 * 2048;

  f32x4 acc[4][3] = {};

  auto stage_A = [&](int t, int h) {
    char* dst = smem + (t & 1) * 16384 + h * 8192;
    int lin = tid * 16;
    int rl  = lin >> 7;
    int col = (lin & 127) ^ ((rl & 7) << 4);
    gload_lds16(Ab + (size_t)(h * 64 + rl) * 2048 + t * 128 + col, dst + lin);
  };
  auto stage_B = [&](int t) {
    char* dst = smem + 32768 + (t & 1) * 24576;
#pragma unroll
    for (int l = 0; l < 3; ++l) {
      int lin = (l * 512 + tid) * 16;
      int rl  = lin >> 7;
      int col = (lin & 127) ^ ((rl & 7) << 4);
      gload_lds16(Bb + (size_t)rl * 2048 + t * 128 + col, dst + lin);
    }
  };

  stage_A(0, 0); stage_A(0, 1);
  stage_B(0);
  stage_B(1);
  asm volatile("s_waitcnt vmcnt(3)" ::: "memory");
  __builtin_amdgcn_s_barrier();

  bf16x8 afr[2][2];
  bf16x8 bfr[3][2];

  for (int t = 0; t < 16; ++t) {
    const char* As = smem + (t & 1) * 16384;
    const char* Bs = smem + 32768 + (t & 1) * 24576;

#pragma unroll
    for (int m = 0; m < 2; ++m) {
      int row = wr * 64 + m * 16 + fr;
#pragma unroll
      for (int ks = 0; ks < 2; ++ks)
        afr[m][ks] = *(const bf16x8*)(As + row * 128 + ((ks * 64 + fq * 16) ^ ((row & 7) << 4)));
    }
#pragma unroll
    for (int n = 0; n < 3; ++n) {
      int row = wc * 48 + n * 16 + fr;
#pragma unroll
      for (int ks = 0; ks < 2; ++ks)
        bfr[n][ks] = *(const bf16x8*)(Bs + row * 128 + ((ks * 64 + fq * 16) ^ ((row & 7) << 4)));
    }
    if (t + 1 < 16) stage_A(t + 1, 0);
    __builtin_amdgcn_s_barrier();
    asm volatile("s_waitcnt lgkmcnt(0)" ::: "memory");
    __builtin_amdgcn_sched_barrier(0);
    __builtin_amdgcn_s_setprio(1);
#pragma unroll
    for (int m = 0; m < 2; ++m)
#pragma unroll
      for (int n = 0; n < 3; ++n)
#pragma unroll
        for (int ks = 0; ks < 2; ++ks)
          acc[m][n] = __builtin_amdgcn_mfma_f32_16x16x32_bf16(afr[m][ks], bfr[n][ks], acc[m][n], 0, 0, 0);
    __builtin_amdgcn_s_setprio(0);
    __builtin_amdgcn_s_barrier();

#pragma unroll
    for (int m = 0; m < 2; ++m) {
      int row = wr * 64 + (m + 2) * 16 + fr;
#pragma unroll
      for (int ks = 0; ks < 2; ++ks)
        afr[m][ks] = *(const bf16x8*)(As + row * 128 + ((ks * 64 + fq * 16) ^ ((row & 7) << 4)));
    }
    if (t + 1 < 16) stage_A(t + 1, 1);
    if (t + 2 < 16) stage_B(t + 2);
    __builtin_amdgcn_s_barrier();
    asm volatile("s_waitcnt lgkmcnt(0)" ::: "memory");
    __builtin_amdgcn_sched_barrier(0);
    __builtin_amdgcn_s_setprio(1);
#pragma unroll
    for (int m = 0; m < 2; ++m)
#pragma unroll
      for (int n = 0; n < 3; ++n)
#pragma unroll
        for (int ks = 0; ks < 2; ++ks)
          acc[m + 2][n] = __builtin_amdgcn_mfma_f32_16x16x32_bf16(afr[m][ks], bfr[n][ks], acc[m + 2][n], 0, 0, 0);
    __builtin_amdgcn_s_setprio(0);
    if (t < 14)       asm volatile("s_waitcnt vmcnt(3)" ::: "memory");
    else if (t == 14) asm volatile("s_waitcnt vmcnt(0)" ::: "memory");
    __builtin_amdgcn_s_barrier();
  }

  const int mbase = m0 + wr * 64;
#pragma unroll
  for (int m = 0; m < 4; ++m)
#pragma unroll
    for (int n = 0; n < 3; ++n) {
      int mB = mbase + m * 16 + fq * 4;
      int ncol = n0 + wc * 48 + n * 16 + fr;
      int sect = ncol >> 10;
      int nn = ncol & 1023;
      int b = mB >> 11, s0 = mB & 2047;
      int h = nn >> 6, hd = nn & 63;
      size_t base = (((size_t)b * 16 + h) * 2048 + s0) * 64 + hd;
      float v0 = acc[m][n][0], v1 = acc[m][n][1], v2 = acc[m][n][2], v3 = acc[m][n][3];
      if (sect == 0) {
        Qws[base]       = f2bf(v0 * SOFT_SCALE);
        Qws[base + 64]  = f2bf(v1 * SOFT_SCALE);
        Qws[base + 128] = f2bf(v2 * SOFT_SCALE);
        Qws[base + 192] = f2bf(v3 * SOFT_SCALE);
      } else if (sect == 1) {
        Kws[base] = f2bf(v0); Kws[base + 64] = f2bf(v1);
        Kws[base + 128] = f2bf(v2); Kws[base + 192] = f2bf(v3);
        out[4194304 + base] = v0; out[4194304 + base + 64] = v1;
        out[4194304 + base + 128] = v2; out[4194304 + base + 192] = v3;
      } else {
        out[8388608 + base] = v0; out[8388608 + base + 64] = v1;
        out[8388608 + base + 128] = v2; out[8388608 + base + 192] = v3;
        size_t tt = ((size_t)(b * 16 + h) * 64 + hd) * 2048 + s0;
        ushort4 pk; pk.x = f2bf(v0); pk.y = f2bf(v1); pk.z = f2bf(v2); pk.w = f2bf(v3);
        *reinterpret_cast<ushort4*>(Vtws + tt) = pk;
      }
    }
}

// ---------------------------------------------------------------------------
// Flash causal attention (NEW): QBLK=128, grid = 16 qb x 32 bh = 512;
// block = 512 (8 waves: wh=wid>>1 q-quarter of 32, wk=wid&1 kv-half of 32).
// One 16KB KV stage feeds 128 q-rows (2x amortization vs r13); wave count
// per CU preserved (2 blocks x 8 waves = 16). Inner body = r13's proven
// 32x32 code. Diagonal mask on last two tiles; wave-uniform skip; 2-way
// cross-wk reduce via dead LDS.
// ---------------------------------------------------------------------------
__global__ __launch_bounds__(512, 4) void attn_kernel(
    const u16* __restrict__ Qw, const u16* __restrict__ Kw,
    const u16* __restrict__ Vtw, u16* __restrict__ Ow) {
  __shared__ __align__(16) char sm[33280];   // K 2x8KB @0; V 2x8KB @16384; Sred @32768
  u16* Ks0 = (u16*)sm;
  u16* Vs0 = (u16*)(sm + 16384);
  float* Sred = (float*)(sm + 32768);        // 128 floats

  const int tid = threadIdx.x, lane = tid & 63, wid = tid >> 6;
  const int wh = wid >> 1, wk = wid & 1;
  const int fq = lane >> 4, fr = lane & 15;
  const int bh = blockIdx.x & 31;
  const int qb = 15 - (blockIdx.x >> 5);     // heavy blocks first
  const int b = bh >> 4, h = bh & 15;
  const int q0 = qb * 128;
  const int qwave = q0 + wh * 32;            // wave's first q row

  const u16* Qbase  = Qw  + (size_t)bh * 2048 * 64;
  const char* Kbase = (const char*)(Kw + (size_t)bh * 2048 * 64);
  const char* VtBase = (const char*)(Vtw + (size_t)bh * 64 * 2048);

  // stage KV tile kt into buffer cc: 512 thr x (1 K-load + 1 V-load)
  auto stageKV = [&](int kt, int cc) {
    int lin = tid * 16;                      // 0..8191
    int row = lin >> 7;
    int logical = lin ^ ((row & 7) << 4);
    gload_lds16(Kbase + (size_t)kt * 8192 + logical, (char*)(Ks0 + cc * 4096) + lin);
    gload_lds16(VtBase + (size_t)row * 4096 + (size_t)kt * 128 + (logical & 127),
                (char*)(Vs0 + cc * 4096) + lin);
  };

  stageKV(0, 0);

  // hoisted Q B-frags: q = qwave + qt*16 + fr (pre-scaled upstream)
  bf16x8 qa[2][2];   // [qt][kh]
#pragma unroll
  for (int qt = 0; qt < 2; ++qt)
#pragma unroll
    for (int kh = 0; kh < 2; ++kh)
      qa[qt][kh] = ldfrag(Qbase + (size_t)(qwave + qt * 16 + fr) * 64 + kh * 32 + fq * 8);

  float ssum[2] = {0.f, 0.f};
  f32x4 accO[2][4] = {};

  const int ktiles = 2 * qb + 2;
  int cur = 0;
  for (int kt = 0; kt < ktiles; ++kt) {
    __syncthreads();   // buf[cur] staged (vmcnt drained); all waves past prev reads

    if (kt + 1 < ktiles) stageKV(kt + 1, cur ^ 1);

    // wave-uniform skip: this wave's q-rows don't reach this KV tile
    if (kt * 64 <= qwave + 31) {
      const u16* Kc = Ks0 + cur * 4096;
      const u16* Vc = Vs0 + cur * 4096;

      // ---- S^T = K Q^T over wave's kv-half x 32 q: 8 MFMA, 4 ds_read
      f32x4 st[2][2];   // [kvt][qt]
      __builtin_amdgcn_s_setprio(1);
#pragma unroll
      for (int kvt = 0; kvt < 2; ++kvt) {
        int krow = wk * 32 + kvt * 16 + fr;
        bf16x8 kf0 = ldfrag(Kc + krow * 64 + ((fq * 8)      ^ ((krow & 7) << 3)));
        bf16x8 kf1 = ldfrag(Kc + krow * 64 + ((fq * 8 + 32) ^ ((krow & 7) << 3)));
#pragma unroll
        for (int qt = 0; qt < 2; ++qt) {
          f32x4 z = {};
          z = __builtin_amdgcn_mfma_f32_16x16x32_bf16(kf0, qa[qt][0], z, 0, 0, 0);
          z = __builtin_amdgcn_mfma_f32_16x16x32_bf16(kf1, qa[qt][1], z, 0, 0, 0);
          st[kvt][qt] = z;
        }
      }
      __builtin_amdgcn_s_setprio(0);

      // ---- p = exp2(s); mask on the last two (diagonal-spanning) tiles
      const bool diag = (kt >= 2 * qb);
      uint32_t W[2][2][2];   // [qt][kvt][hh]
#pragma unroll
      for (int qt = 0; qt < 2; ++qt) {
        int qrow = qwave + qt * 16 + fr;
#pragma unroll
        for (int kvt = 0; kvt < 2; ++kvt) {
          float p0, p1, p2, p3;
          if (!diag) {
            p0 = exp2f(st[kvt][qt][0]);
            p1 = exp2f(st[kvt][qt][1]);
            p2 = exp2f(st[kvt][qt][2]);
            p3 = exp2f(st[kvt][qt][3]);
          } else {
            int kvg = kt * 64 + wk * 32 + kvt * 16 + fq * 4;
            p0 = (kvg + 0 > qrow) ? 0.f : exp2f(st[kvt][qt][0]);
            p1 = (kvg + 1 > qrow) ? 0.f : exp2f(st[kvt][qt][1]);
            p2 = (kvg + 2 > qrow) ? 0.f : exp2f(st[kvt][qt][2]);
            p3 = (kvg + 3 > qrow) ? 0.f : exp2f(st[kvt][qt][3]);
          }
          ssum[qt] += (p0 + p1) + (p2 + p3);
          W[qt][kvt][0] = cvt_pk_bf16(p0, p1);
          W[qt][kvt][1] = cvt_pk_bf16(p2, p3);
        }
      }

      // ---- permlane P redistribution per qt (kv-local 0..31)
      union U { uint32_t u[4]; bf16x8 v; };
      U pa[2];
#pragma unroll
      for (int qt = 0; qt < 2; ++qt)
#pragma unroll
        for (int hh = 0; hh < 2; ++hh) {
          uint32_t a0 = W[qt][0][hh], b0 = W[qt][1][hh];
          asm("v_permlane32_swap_b32 %0, %1" : "+v"(a0), "+v"(b0));
          asm("v_permlane16_swap_b32 %0, %1" : "+v"(a0), "+v"(b0));
          pa[qt].u[hh] = a0; pa[qt].u[2 + hh] = b0;
        }

      // ---- O += P V over wave's kv-half: 8 MFMA, 4 ds_read
      __builtin_amdgcn_s_setprio(1);
#pragma unroll
      for (int ht = 0; ht < 4; ++ht) {
        int vrow = ht * 16 + fr;
        bf16x8 vb = ldfrag(Vc + vrow * 64 + ((wk * 32 + fq * 8) ^ ((vrow & 7) << 3)));
#pragma unroll
        for (int qt = 0; qt < 2; ++qt)
          accO[qt][ht] = __builtin_amdgcn_mfma_f32_16x16x32_bf16(pa[qt].v, vb, accO[qt][ht], 0, 0, 0);
      }
      __builtin_amdgcn_s_setprio(0);
    }
    cur ^= 1;
  }

  // ---- wave-local ssum reduce over fq copies
#pragma unroll
  for (int qt = 0; qt < 2; ++qt) {
    ssum[qt] += __shfl_xor(ssum[qt], 16);
    ssum[qt] += __shfl_xor(ssum[qt], 32);
  }

  // ---- cross-wk reduce via dead K/V LDS (Ored spans the whole 32KB block)
  __syncthreads();
  float* Ored = (float*)sm;   // 8192 floats: slot = (wh*2+qt)*4+ht (0..31), 256 floats each
  if (wk == 1) {
#pragma unroll
    for (int qt = 0; qt < 2; ++qt)
#pragma unroll
      for (int ht = 0; ht < 4; ++ht)
        *reinterpret_cast<f32x4*>(&Ored[(((wh * 2 + qt) * 4 + ht) << 8) + lane * 4]) = accO[qt][ht];
    if (fq == 0) {
      Sred[wh * 32 + fr]      = ssum[0];
      Sred[wh * 32 + 16 + fr] = ssum[1];
    }
  }
  __syncthreads();
  if (wk == 0) {
#pragma unroll
    for (int qt = 0; qt < 2; ++qt)
#pragma unroll
      for (int ht = 0; ht < 4; ++ht) {
        f32x4 o = *reinterpret_cast<const f32x4*>(&Ored[(((wh * 2 + qt) * 4 + ht) << 8) + lane * 4]);
        accO[qt][ht] += o;
      }
    float invq[2][4];
#pragma unroll
    for (int qt = 0; qt < 2; ++qt) {
      float s = ssum[qt] + Sred[wh * 32 + qt * 16 + fr];
      float inv = 1.0f / s;                  // for q = qwave + qt*16 + fr
#pragma unroll
      for (int r = 0; r < 4; ++r) invq[qt][r] = __shfl(inv, fq * 4 + r);
    }
#pragma unroll
    for (int qt = 0; qt < 2; ++qt)
#pragma unroll
      for (int ht = 0; ht < 4; ++ht)
#pragma unroll
        for (int r = 0; r < 4; ++r) {
          float o = accO[qt][ht][r] * invq[qt][r];
          int qr = qwave + qt * 16 + fq * 4 + r;
          Ow[((size_t)b * 2048 + qr) * 1024 + h * 64 + ht * 16 + fr] = f2bf(o);
        }
  }
}

// ---------------------------------------------------------------------------
// Output projection (r19 2-phase, validated): 128x128, grid 256, 64KB LDS.
// ---------------------------------------------------------------------------
__global__ __launch_bounds__(512, 2) void proj_gemm_kernel(
    const u16* __restrict__ Ob, const u16* __restrict__ Wob,
    const float* __restrict__ bias, float* __restrict__ out) {
  extern __shared__ char smem[];   // A 2x16KB @0; B 2x16KB @32768

  const int tid = threadIdx.x, lane = tid & 63, wid = tid >> 6;
  const int wr = wid >> 2, wc = wid & 3;
  const int fq = lane >> 4, fr = lane & 15;

  const int wg = (blockIdx.x & 7) * 32 + (blockIdx.x >> 3);
  const int bm = wg >> 3, bn = wg & 7;
  const int m0 = bm * 128, n0 = bn * 128;

  const char* Ab = (const char*)Ob  + (size_t)m0 * 2048;
  const char* Bb = (const char*)Wob + (size_t)n0 * 2048;

  f32x4 acc[4][2] = {};

  auto stage = [&](int t, int mat, int h) {
    char* dst = smem + mat * 32768 + (t & 1) * 16384 + h * 8192;
    const char* src = mat ? Bb : Ab;
    int lin = tid * 16;
    int rl  = lin >> 7;
    int col = (lin & 127) ^ ((rl & 7) << 4);
    gload_lds16(src + (size_t)(h * 64 + rl) * 2048 + t * 128 + col, dst + lin);
  };

  stage(0, 0, 0); stage(0, 0, 1);
  stage(0, 1, 0); stage(0, 1, 1);
  stage(1, 1, 0); stage(1, 1, 1);
  asm volatile("s_waitcnt vmcnt(2)" ::: "memory");
  __builtin_amdgcn_s_barrier();

  bf16x8 afr[2][2];
  bf16x8 bfr[2][2];

  for (int t = 0; t < 16; ++t) {
    const char* As = smem + (t & 1) * 16384;
    const char* Bs = smem + 32768 + (t & 1) * 16384;

#pragma unroll
    for (int m = 0; m < 2; ++m) {
      int row = wr * 64 + m * 16 + fr;
#pragma unroll
      for (int ks = 0; ks < 2; ++ks)
        afr[m][ks] = *(const bf16x8*)(As + row * 128 + ((ks * 64 + fq * 16) ^ ((row & 7) << 4)));
    }
#pragma unroll
    for (int n = 0; n < 2; ++n) {
      int row = wc * 32 + n * 16 + fr;
#pragma unroll
      for (int ks = 0; ks < 2; ++ks)
        bfr[n][ks] = *(const bf16x8*)(Bs + row * 128 + ((ks * 64 + fq * 16) ^ ((row & 7) << 4)));
    }
    if (t + 1 < 16) stage(t + 1, 0, 0);
    __builtin_amdgcn_s_barrier();
    asm volatile("s_waitcnt lgkmcnt(0)" ::: "memory");
    __builtin_amdgcn_sched_barrier(0);
    __builtin_amdgcn_s_setprio(1);
#pragma unroll
    for (int m = 0; m < 2; ++m)
#pragma unroll
      for (int n = 0; n < 2; ++n)
#pragma unroll
        for (int ks = 0; ks < 2; ++ks)
          acc[m][n] = __builtin_amdgcn_mfma_f32_16x16x32_bf16(afr[m][ks], bfr[n][ks], acc[m][n], 0, 0, 0);
    __builtin_amdgcn_s_setprio(0);
    __builtin_amdgcn_s_barrier();

#pragma unroll
    for (int m = 0; m < 2; ++m) {
      int row = wr * 64 + (m + 2) * 16 + fr;
#pragma unroll
      for (int ks = 0; ks < 2; ++ks)
        afr[m][ks] = *(const bf16x8*)(As + row * 128 + ((ks * 64 + fq * 16) ^ ((row & 7) << 4)));
    }
    if (t + 1 < 16) stage(t + 1, 0, 1);
    if (t + 2 < 16) { stage(t + 2, 1, 0); stage(t + 2, 1, 1); }
    __builtin_amdgcn_s_barrier();
    asm volatile("s_waitcnt lgkmcnt(0)" ::: "memory");
    __builtin_amdgcn_sched_barrier(0);
    __builtin_amdgcn_s_setprio(1);
#pragma unroll
    for (int m = 0; m < 2; ++m)
#pragma unroll
      for (int n = 0; n < 2; ++n)
#pragma unroll
        for (int ks = 0; ks < 2; ++ks)
          acc[m + 2][n] = __builtin_amdgcn_mfma_f32_16x16x32_bf16(afr[m][ks], bfr[n][ks], acc[m + 2][n], 0, 0, 0);
    __builtin_amdgcn_s_setprio(0);
    if (t < 14)       asm volatile("s_waitcnt vmcnt(2)" ::: "memory");
    else if (t == 14) asm volatile("s_waitcnt vmcnt(0)" ::: "memory");
    __builtin_amdgcn_s_barrier();
  }

  const int mbase = m0 + wr * 64;
#pragma unroll
  for (int m = 0; m < 4; ++m)
#pragma unroll
    for (int n = 0; n < 2; ++n) {
      int mB = mbase + m * 16 + fq * 4;
      int ncol = n0 + wc * 32 + n * 16 + fr;
      float bv = bias[ncol];
#pragma unroll
      for (int r = 0; r < 4; ++r)
        out[(size_t)(mB + r) * 1024 + ncol] = acc[m][n][r] + bv;
    }
}

// ---------------------------------------------------------------------------
extern "C" void kernel_launch(void* const* d_in, const int* in_sizes, int n_in,
                              void* d_out, int out_size, void* d_ws, size_t ws_size,
                              hipStream_t stream) {
  const float* x    = (const float*)d_in[0];
  const float* wqkv = (const float*)d_in[1];
  const float* wo   = (const float*)d_in[2];
  const float* wo_b = (const float*)d_in[3];
  float* out = (float*)d_out;

  u16* xb    = (u16*)d_ws;            // 4096*1024
  u16* wqkvb = xb    + 4194304;       // 3072*1024
  u16* wob   = wqkvb + 3145728;       // 1024*1024
  u16* q_ws  = wob   + 1048576;       // [2,16,2048,64] (pre-scaled)
  u16* k_ws  = q_ws  + 4194304;       // [2,16,2048,64]
  u16* vt_ws = k_ws  + 4194304;       // [2,16,64,2048]  (V^T)
  u16* o_ws  = vt_ws + 4194304;       // [4096,1024]

  static bool attr_set = false;
  if (!attr_set) {
    hipFuncSetAttribute((const void*)qkv_gemm_kernel,
                        hipFuncAttributeMaxDynamicSharedMemorySize, 131072);
    hipFuncSetAttribute((const void*)proj_gemm_kernel,
                        hipFuncAttributeMaxDynamicSharedMemorySize, 65536);
    attr_set = true;
  }

  cvt_all<<<2048, 256, 0, stream>>>(x, wqkv, wo, xb, wqkvb, wob);
  qkv_gemm_kernel<<<512, 512, 81920, stream>>>(xb, wqkvb, q_ws, k_ws, vt_ws, out);
  attn_kernel<<<16 * 32, 512, 0, stream>>>(q_ws, k_ws, vt_ws, o_ws);
  proj_gemm_kernel<<<256, 512, 65536, stream>>>(o_ws, wob, wo_b, out);
}

// Round 21
// 104.655 us; speedup vs baseline: 1.0067x; 1.0067x over previous
//
#include <hip/hip_runtime.h>
#include <cstdint>
#include <cstddef>

// ---------------------------------------------------------------------------
// MHA forward: x[2,2048,1024] fp32, wqkv[3072,1024], wo[1024,1024], wo_b[1024]
// out = concat(y[2,2048,1024], k[2,16,2048,64], v[2,16,2048,64]) fp32
// FINAL (r19 best-measured, 104.8us): cvt->bf16 (fused); QKV GEMM (128x192,
// 2 blocks/CU, 2-phase fine interleave, counted vmcnt(3), Q pre-scaled);
// flash causal attn (r13: kv-half x q-half waves, swapped QK^T, permlane
// in-reg P, no-max softmax); proj GEMM (128x128 2-phase, vmcnt(2)).
// ---------------------------------------------------------------------------

using bf16x8 = __attribute__((ext_vector_type(8))) __bf16;
using f32x4  = __attribute__((ext_vector_type(4))) float;
using u16    = unsigned short;

#define SOFT_SCALE 0.1803368801111244f   // 0.125 * log2(e)  (attn in exp2 domain)

// fp32 -> bf16 bits, round-to-nearest-even
__device__ __forceinline__ u16 f2bf(float f) {
  union { float f; uint32_t u; } a; a.f = f;
  uint32_t r = a.u + 0x7fffu + ((a.u >> 16) & 1u);
  return (u16)(r >> 16);
}

__device__ __forceinline__ bf16x8 ldfrag(const u16* p) {
  return *reinterpret_cast<const bf16x8*>(p);
}

__device__ __forceinline__ void gload_lds16(const void* g, void* l) {
  __builtin_amdgcn_global_load_lds((const __attribute__((address_space(1))) void*)g,
                                   (__attribute__((address_space(3))) void*)l,
                                   16, 0, 0);
}

// pack two fp32 -> one u32 of two bf16 (lo = a, hi = b), RNE
__device__ __forceinline__ uint32_t cvt_pk_bf16(float a, float b) {
  uint32_t r;
  asm("v_cvt_pk_bf16_f32 %0, %1, %2" : "=v"(r) : "v"(a), "v"(b));
  return r;
}

// ---------------------------------------------------------------------------
// fused fp32 -> bf16 convert for x, wqkv, wo (single launch)
// ---------------------------------------------------------------------------
__global__ void cvt_all(const float* __restrict__ x, const float* __restrict__ wqkv,
                        const float* __restrict__ wo,
                        u16* __restrict__ xb, u16* __restrict__ wqkvb, u16* __restrict__ wob) {
  int i = blockIdx.x * blockDim.x + threadIdx.x;
  int stride = gridDim.x * blockDim.x;
  for (; i < 2097152; i += stride) {
    const float* src; u16* dst; int j;
    if (i < 1048576)      { src = x;    dst = xb;    j = i; }
    else if (i < 1835008) { src = wqkv; dst = wqkvb; j = i - 1048576; }
    else                  { src = wo;   dst = wob;   j = i - 1835008; }
    float4 v = reinterpret_cast<const float4*>(src)[j];
    ushort4 o;
    o.x = f2bf(v.x); o.y = f2bf(v.y); o.z = f2bf(v.z); o.w = f2bf(v.w);
    reinterpret_cast<ushort4*>(dst)[j] = o;
  }
}

// ---------------------------------------------------------------------------
// QKV GEMM (r15, validated): 128x192 tiles, grid 512 = 2/CU, 80KB LDS,
// 2-phase fine interleave, counted vmcnt(3), Q pre-scaled.
// ---------------------------------------------------------------------------
__global__ __launch_bounds__(512, 2) void qkv_gemm_kernel(
    const u16* __restrict__ Xb, const u16* __restrict__ Wb,
    u16* __restrict__ Qws, u16* __restrict__ Kws, u16* __restrict__ Vtws,
    float* __restrict__ out) {
  extern __shared__ char smem[];

  const int tid = threadIdx.x, lane = tid & 63, wid = tid >> 6;
  const int wr = wid >> 2, wc = wid & 3;
  const int fq = lane >> 4, fr = lane & 15;

  // bijective chunked XCD swizzle (512 % 8 == 0)
  const int wg = (blockIdx.x & 7) * 64 + (blockIdx.x >> 3);
  const int bm = wg >> 4, bn = wg & 15;
  const int m0 = bm * 128, n0 = bn * 192;

  const char* Ab = (const char*)Xb + (size_t)m0 * 2048;
  const char* Bb = (const char*)Wb + (size_t)n0 * 2048;

  f32x4 acc[4][3] = {};

  auto stage_A = [&](int t, int h) {
    char* dst = smem + (t & 1) * 16384 + h * 8192;
    int lin = tid * 16;
    int rl  = lin >> 7;
    int col = (lin & 127) ^ ((rl & 7) << 4);
    gload_lds16(Ab + (size_t)(h * 64 + rl) * 2048 + t * 128 + col, dst + lin);
  };
  auto stage_B = [&](int t) {
    char* dst = smem + 32768 + (t & 1) * 24576;
#pragma unroll
    for (int l = 0; l < 3; ++l) {
      int lin = (l * 512 + tid) * 16;
      int rl  = lin >> 7;
      int col = (lin & 127) ^ ((rl & 7) << 4);
      gload_lds16(Bb + (size_t)rl * 2048 + t * 128 + col, dst + lin);
    }
  };

  stage_A(0, 0); stage_A(0, 1);
  stage_B(0);
  stage_B(1);
  asm volatile("s_waitcnt vmcnt(3)" ::: "memory");
  __builtin_amdgcn_s_barrier();

  bf16x8 afr[2][2];
  bf16x8 bfr[3][2];

  for (int t = 0; t < 16; ++t) {
    const char* As = smem + (t & 1) * 16384;
    const char* Bs = smem + 32768 + (t & 1) * 24576;

#pragma unroll
    for (int m = 0; m < 2; ++m) {
      int row = wr * 64 + m * 16 + fr;
#pragma unroll
      for (int ks = 0; ks < 2; ++ks)
        afr[m][ks] = *(const bf16x8*)(As + row * 128 + ((ks * 64 + fq * 16) ^ ((row & 7) << 4)));
    }
#pragma unroll
    for (int n = 0; n < 3; ++n) {
      int row = wc * 48 + n * 16 + fr;
#pragma unroll
      for (int ks = 0; ks < 2; ++ks)
        bfr[n][ks] = *(const bf16x8*)(Bs + row * 128 + ((ks * 64 + fq * 16) ^ ((row & 7) << 4)));
    }
    if (t + 1 < 16) stage_A(t + 1, 0);
    __builtin_amdgcn_s_barrier();
    asm volatile("s_waitcnt lgkmcnt(0)" ::: "memory");
    __builtin_amdgcn_sched_barrier(0);
    __builtin_amdgcn_s_setprio(1);
#pragma unroll
    for (int m = 0; m < 2; ++m)
#pragma unroll
      for (int n = 0; n < 3; ++n)
#pragma unroll
        for (int ks = 0; ks < 2; ++ks)
          acc[m][n] = __builtin_amdgcn_mfma_f32_16x16x32_bf16(afr[m][ks], bfr[n][ks], acc[m][n], 0, 0, 0);
    __builtin_amdgcn_s_setprio(0);
    __builtin_amdgcn_s_barrier();

#pragma unroll
    for (int m = 0; m < 2; ++m) {
      int row = wr * 64 + (m + 2) * 16 + fr;
#pragma unroll
      for (int ks = 0; ks < 2; ++ks)
        afr[m][ks] = *(const bf16x8*)(As + row * 128 + ((ks * 64 + fq * 16) ^ ((row & 7) << 4)));
    }
    if (t + 1 < 16) stage_A(t + 1, 1);
    if (t + 2 < 16) stage_B(t + 2);
    __builtin_amdgcn_s_barrier();
    asm volatile("s_waitcnt lgkmcnt(0)" ::: "memory");
    __builtin_amdgcn_sched_barrier(0);
    __builtin_amdgcn_s_setprio(1);
#pragma unroll
    for (int m = 0; m < 2; ++m)
#pragma unroll
      for (int n = 0; n < 3; ++n)
#pragma unroll
        for (int ks = 0; ks < 2; ++ks)
          acc[m + 2][n] = __builtin_amdgcn_mfma_f32_16x16x32_bf16(afr[m][ks], bfr[n][ks], acc[m + 2][n], 0, 0, 0);
    __builtin_amdgcn_s_setprio(0);
    if (t < 14)       asm volatile("s_waitcnt vmcnt(3)" ::: "memory");
    else if (t == 14) asm volatile("s_waitcnt vmcnt(0)" ::: "memory");
    __builtin_amdgcn_s_barrier();
  }

  const int mbase = m0 + wr * 64;
#pragma unroll
  for (int m = 0; m < 4; ++m)
#pragma unroll
    for (int n = 0; n < 3; ++n) {
      int mB = mbase + m * 16 + fq * 4;
      int ncol = n0 + wc * 48 + n * 16 + fr;
      int sect = ncol >> 10;
      int nn = ncol & 1023;
      int b = mB >> 11, s0 = mB & 2047;
      int h = nn >> 6, hd = nn & 63;
      size_t base = (((size_t)b * 16 + h) * 2048 + s0) * 64 + hd;
      float v0 = acc[m][n][0], v1 = acc[m][n][1], v2 = acc[m][n][2], v3 = acc[m][n][3];
      if (sect == 0) {
        Qws[base]       = f2bf(v0 * SOFT_SCALE);
        Qws[base + 64]  = f2bf(v1 * SOFT_SCALE);
        Qws[base + 128] = f2bf(v2 * SOFT_SCALE);
        Qws[base + 192] = f2bf(v3 * SOFT_SCALE);
      } else if (sect == 1) {
        Kws[base] = f2bf(v0); Kws[base + 64] = f2bf(v1);
        Kws[base + 128] = f2bf(v2); Kws[base + 192] = f2bf(v3);
        out[4194304 + base] = v0; out[4194304 + base + 64] = v1;
        out[4194304 + base + 128] = v2; out[4194304 + base + 192] = v3;
      } else {
        out[8388608 + base] = v0; out[8388608 + base + 64] = v1;
        out[8388608 + base + 128] = v2; out[8388608 + base + 192] = v3;
        size_t tt = ((size_t)(b * 16 + h) * 64 + hd) * 2048 + s0;
        ushort4 pk; pk.x = f2bf(v0); pk.y = f2bf(v1); pk.z = f2bf(v2); pk.w = f2bf(v3);
        *reinterpret_cast<ushort4*>(Vtws + tt) = pk;
      }
    }
}

// ---------------------------------------------------------------------------
// Flash causal attention (r13, plateau 44.5us). grid = 1024; block = 256.
// Wave (wk,wh) owns kv-half wk x q-half wh. Swapped QK^T, permlane in-reg P,
// no-max softmax (Q pre-scaled), end-only cross-wk reduce via dead LDS.
// ---------------------------------------------------------------------------
__global__ __launch_bounds__(256, 4) void attn_kernel(
    const u16* __restrict__ Qw, const u16* __restrict__ Kw,
    const u16* __restrict__ Vtw, u16* __restrict__ Ow) {
  __shared__ u16 Ks[2][64 * 64];
  __shared__ u16 Vs[2][64 * 64];

  const int tid = threadIdx.x, lane = tid & 63, wid = tid >> 6;
  const int wk = wid >> 1, wh = wid & 1;
  const int fq = lane >> 4, fr = lane & 15;
  const int bh = blockIdx.x & 31;
  const int qb = 31 - (blockIdx.x >> 5);
  const int b = bh >> 4, h = bh & 15;
  const int q0 = qb * 64;

  const u16* Qbase  = Qw  + (size_t)bh * 2048 * 64;
  const u16* Kbase  = Kw  + (size_t)bh * 2048 * 64;
  const char* VtBase = (const char*)(Vtw + (size_t)bh * 64 * 2048);

#pragma unroll
  for (int f = 0; f < 2; ++f) {
    int lin = (f * 256 + tid) * 16;
    int row = lin >> 7;
    int logical = lin ^ ((row & 7) << 4);
    gload_lds16((const char*)Kbase + logical, (char*)Ks[0] + lin);
    gload_lds16(VtBase + (size_t)row * 4096 + (logical & 127), (char*)Vs[0] + lin);
  }

  bf16x8 qa[2][2];
#pragma unroll
  for (int qt = 0; qt < 2; ++qt)
#pragma unroll
    for (int kh = 0; kh < 2; ++kh)
      qa[qt][kh] = ldfrag(Qbase + (size_t)(q0 + wh * 32 + qt * 16 + fr) * 64 + kh * 32 + fq * 8);

  float ssum[2] = {0.f, 0.f};
  f32x4 accO[2][4] = {};

  int cur = 0;
  for (int kb = 0; kb <= qb; ++kb) {
    __syncthreads();

    if (kb < qb) {
      const char* kg = (const char*)(Kbase + (size_t)(kb + 1) * 64 * 64);
#pragma unroll
      for (int f = 0; f < 2; ++f) {
        int lin = (f * 256 + tid) * 16;
        int row = lin >> 7;
        int logical = lin ^ ((row & 7) << 4);
        gload_lds16(kg + logical, (char*)Ks[cur ^ 1] + lin);
        gload_lds16(VtBase + (size_t)row * 4096 + (size_t)(kb + 1) * 128 + (logical & 127),
                    (char*)Vs[cur ^ 1] + lin);
      }
    }

    const u16* Kc = Ks[cur];
    const u16* Vc = Vs[cur];

    f32x4 st[2][2];
    __builtin_amdgcn_s_setprio(1);
#pragma unroll
    for (int kvt = 0; kvt < 2; ++kvt) {
      int krow = wk * 32 + kvt * 16 + fr;
      bf16x8 kf0 = ldfrag(Kc + krow * 64 + ((fq * 8)      ^ ((krow & 7) << 3)));
      bf16x8 kf1 = ldfrag(Kc + krow * 64 + ((fq * 8 + 32) ^ ((krow & 7) << 3)));
#pragma unroll
      for (int qt = 0; qt < 2; ++qt) {
        f32x4 z = {};
        z = __builtin_amdgcn_mfma_f32_16x16x32_bf16(kf0, qa[qt][0], z, 0, 0, 0);
        z = __builtin_amdgcn_mfma_f32_16x16x32_bf16(kf1, qa[qt][1], z, 0, 0, 0);
        st[kvt][qt] = z;
      }
    }
    __builtin_amdgcn_s_setprio(0);

    uint32_t W[2][2][2];
#pragma unroll
    for (int qt = 0; qt < 2; ++qt) {
      int qrow = q0 + wh * 32 + qt * 16 + fr;
#pragma unroll
      for (int kvt = 0; kvt < 2; ++kvt) {
        float p0, p1, p2, p3;
        if (kb < qb) {
          p0 = exp2f(st[kvt][qt][0]);
          p1 = exp2f(st[kvt][qt][1]);
          p2 = exp2f(st[kvt][qt][2]);
          p3 = exp2f(st[kvt][qt][3]);
        } else {
          int kvg = kb * 64 + wk * 32 + kvt * 16 + fq * 4;
          p0 = (kvg + 0 > qrow) ? 0.f : exp2f(st[kvt][qt][0]);
          p1 = (kvg + 1 > qrow) ? 0.f : exp2f(st[kvt][qt][1]);
          p2 = (kvg + 2 > qrow) ? 0.f : exp2f(st[kvt][qt][2]);
          p3 = (kvg + 3 > qrow) ? 0.f : exp2f(st[kvt][qt][3]);
        }
        ssum[qt] += (p0 + p1) + (p2 + p3);
        W[qt][kvt][0] = cvt_pk_bf16(p0, p1);
        W[qt][kvt][1] = cvt_pk_bf16(p2, p3);
      }
    }

    union U { uint32_t u[4]; bf16x8 v; };
    U pa[2];
#pragma unroll
    for (int qt = 0; qt < 2; ++qt)
#pragma unroll
      for (int hh = 0; hh < 2; ++hh) {
        uint32_t a0 = W[qt][0][hh], b0 = W[qt][1][hh];
        asm("v_permlane32_swap_b32 %0, %1" : "+v"(a0), "+v"(b0));
        asm("v_permlane16_swap_b32 %0, %1" : "+v"(a0), "+v"(b0));
        pa[qt].u[hh] = a0; pa[qt].u[2 + hh] = b0;
      }

    __builtin_amdgcn_s_setprio(1);
#pragma unroll
    for (int ht = 0; ht < 4; ++ht) {
      int vrow = ht * 16 + fr;
      bf16x8 vb = ldfrag(Vc + vrow * 64 + ((wk * 32 + fq * 8) ^ ((vrow & 7) << 3)));
#pragma unroll
      for (int qt = 0; qt < 2; ++qt)
        accO[qt][ht] = __builtin_amdgcn_mfma_f32_16x16x32_bf16(pa[qt].v, vb, accO[qt][ht], 0, 0, 0);
    }
    __builtin_amdgcn_s_setprio(0);
    cur ^= 1;
  }

#pragma unroll
  for (int qt = 0; qt < 2; ++qt) {
    ssum[qt] += __shfl_xor(ssum[qt], 16);
    ssum[qt] += __shfl_xor(ssum[qt], 32);
  }

  __syncthreads();
  float* Ored = (float*)Ks;
  float* Sred = (float*)Vs;
  if (wk == 1) {
#pragma unroll
    for (int qt = 0; qt < 2; ++qt)
#pragma unroll
      for (int ht = 0; ht < 4; ++ht)
        *reinterpret_cast<f32x4*>(&Ored[(((wh * 2 + qt) * 4 + ht) << 8) + lane * 4]) = accO[qt][ht];
    if (fq == 0) {
      Sred[wh * 64 + fr]      = ssum[0];
      Sred[wh * 64 + 16 + fr] = ssum[1];
    }
  }
  __syncthreads();
  if (wk == 0) {
#pragma unroll
    for (int qt = 0; qt < 2; ++qt)
#pragma unroll
      for (int ht = 0; ht < 4; ++ht) {
        f32x4 o = *reinterpret_cast<const f32x4*>(&Ored[(((wh * 2 + qt) * 4 + ht) << 8) + lane * 4]);
        accO[qt][ht] += o;
      }
    float invq[2][4];
#pragma unroll
    for (int qt = 0; qt < 2; ++qt) {
      float s = ssum[qt] + Sred[wh * 64 + qt * 16 + fr];
      float inv = 1.0f / s;
#pragma unroll
      for (int r = 0; r < 4; ++r) invq[qt][r] = __shfl(inv, fq * 4 + r);
    }
#pragma unroll
    for (int qt = 0; qt < 2; ++qt)
#pragma unroll
      for (int ht = 0; ht < 4; ++ht)
#pragma unroll
        for (int r = 0; r < 4; ++r) {
          float o = accO[qt][ht][r] * invq[qt][r];
          int qr = q0 + wh * 32 + qt * 16 + fq * 4 + r;
          Ow[((size_t)b * 2048 + qr) * 1024 + h * 64 + ht * 16 + fr] = f2bf(o);
        }
  }
}

// ---------------------------------------------------------------------------
// Output projection (r19 2-phase, validated): 128x128, grid 256, 64KB LDS.
// ---------------------------------------------------------------------------
__global__ __launch_bounds__(512, 2) void proj_gemm_kernel(
    const u16* __restrict__ Ob, const u16* __restrict__ Wob,
    const float* __restrict__ bias, float* __restrict__ out) {
  extern __shared__ char smem[];   // A 2x16KB @0; B 2x16KB @32768

  const int tid = threadIdx.x, lane = tid & 63, wid = tid >> 6;
  const int wr = wid >> 2, wc = wid & 3;
  const int fq = lane >> 4, fr = lane & 15;

  const int wg = (blockIdx.x & 7) * 32 + (blockIdx.x >> 3);
  const int bm = wg >> 3, bn = wg & 7;
  const int m0 = bm * 128, n0 = bn * 128;

  const char* Ab = (const char*)Ob  + (size_t)m0 * 2048;
  const char* Bb = (const char*)Wob + (size_t)n0 * 2048;

  f32x4 acc[4][2] = {};

  auto stage = [&](int t, int mat, int h) {
    char* dst = smem + mat * 32768 + (t & 1) * 16384 + h * 8192;
    const char* src = mat ? Bb : Ab;
    int lin = tid * 16;
    int rl  = lin >> 7;
    int col = (lin & 127) ^ ((rl & 7) << 4);
    gload_lds16(src + (size_t)(h * 64 + rl) * 2048 + t * 128 + col, dst + lin);
  };

  stage(0, 0, 0); stage(0, 0, 1);
  stage(0, 1, 0); stage(0, 1, 1);
  stage(1, 1, 0); stage(1, 1, 1);
  asm volatile("s_waitcnt vmcnt(2)" ::: "memory");
  __builtin_amdgcn_s_barrier();

  bf16x8 afr[2][2];
  bf16x8 bfr[2][2];

  for (int t = 0; t < 16; ++t) {
    const char* As = smem + (t & 1) * 16384;
    const char* Bs = smem + 32768 + (t & 1) * 16384;

#pragma unroll
    for (int m = 0; m < 2; ++m) {
      int row = wr * 64 + m * 16 + fr;
#pragma unroll
      for (int ks = 0; ks < 2; ++ks)
        afr[m][ks] = *(const bf16x8*)(As + row * 128 + ((ks * 64 + fq * 16) ^ ((row & 7) << 4)));
    }
#pragma unroll
    for (int n = 0; n < 2; ++n) {
      int row = wc * 32 + n * 16 + fr;
#pragma unroll
      for (int ks = 0; ks < 2; ++ks)
        bfr[n][ks] = *(const bf16x8*)(Bs + row * 128 + ((ks * 64 + fq * 16) ^ ((row & 7) << 4)));
    }
    if (t + 1 < 16) stage(t + 1, 0, 0);
    __builtin_amdgcn_s_barrier();
    asm volatile("s_waitcnt lgkmcnt(0)" ::: "memory");
    __builtin_amdgcn_sched_barrier(0);
    __builtin_amdgcn_s_setprio(1);
#pragma unroll
    for (int m = 0; m < 2; ++m)
#pragma unroll
      for (int n = 0; n < 2; ++n)
#pragma unroll
        for (int ks = 0; ks < 2; ++ks)
          acc[m][n] = __builtin_amdgcn_mfma_f32_16x16x32_bf16(afr[m][ks], bfr[n][ks], acc[m][n], 0, 0, 0);
    __builtin_amdgcn_s_setprio(0);
    __builtin_amdgcn_s_barrier();

#pragma unroll
    for (int m = 0; m < 2; ++m) {
      int row = wr * 64 + (m + 2) * 16 + fr;
#pragma unroll
      for (int ks = 0; ks < 2; ++ks)
        afr[m][ks] = *(const bf16x8*)(As + row * 128 + ((ks * 64 + fq * 16) ^ ((row & 7) << 4)));
    }
    if (t + 1 < 16) stage(t + 1, 0, 1);
    if (t + 2 < 16) { stage(t + 2, 1, 0); stage(t + 2, 1, 1); }
    __builtin_amdgcn_s_barrier();
    asm volatile("s_waitcnt lgkmcnt(0)" ::: "memory");
    __builtin_amdgcn_sched_barrier(0);
    __builtin_amdgcn_s_setprio(1);
#pragma unroll
    for (int m = 0; m < 2; ++m)
#pragma unroll
      for (int n = 0; n < 2; ++n)
#pragma unroll
        for (int ks = 0; ks < 2; ++ks)
          acc[m + 2][n] = __builtin_amdgcn_mfma_f32_16x16x32_bf16(afr[m][ks], bfr[n][ks], acc[m + 2][n], 0, 0, 0);
    __builtin_amdgcn_s_setprio(0);
    if (t < 14)       asm volatile("s_waitcnt vmcnt(2)" ::: "memory");
    else if (t == 14) asm volatile("s_waitcnt vmcnt(0)" ::: "memory");
    __builtin_amdgcn_s_barrier();
  }

  const int mbase = m0 + wr * 64;
#pragma unroll
  for (int m = 0; m < 4; ++m)
#pragma unroll
    for (int n = 0; n < 2; ++n) {
      int mB = mbase + m * 16 + fq * 4;
      int ncol = n0 + wc * 32 + n * 16 + fr;
      float bv = bias[ncol];
#pragma unroll
      for (int r = 0; r < 4; ++r)
        out[(size_t)(mB + r) * 1024 + ncol] = acc[m][n][r] + bv;
    }
}

// ---------------------------------------------------------------------------
extern "C" void kernel_launch(void* const* d_in, const int* in_sizes, int n_in,
                              void* d_out, int out_size, void* d_ws, size_t ws_size,
                              hipStream_t stream) {
  const float* x    = (const float*)d_in[0];
  const float* wqkv = (const float*)d_in[1];
  const float* wo   = (const float*)d_in[2];
  const float* wo_b = (const float*)d_in[3];
  float* out = (float*)d_out;

  u16* xb    = (u16*)d_ws;            // 4096*1024
  u16* wqkvb = xb    + 4194304;       // 3072*1024
  u16* wob   = wqkvb + 3145728;       // 1024*1024
  u16* q_ws  = wob   + 1048576;       // [2,16,2048,64] (pre-scaled)
  u16* k_ws  = q_ws  + 4194304;       // [2,16,2048,64]
  u16* vt_ws = k_ws  + 4194304;       // [2,16,64,2048]  (V^T)
  u16* o_ws  = vt_ws + 4194304;       // [4096,1024]

  static bool attr_set = false;
  if (!attr_set) {
    hipFuncSetAttribute((const void*)qkv_gemm_kernel,
                        hipFuncAttributeMaxDynamicSharedMemorySize, 131072);
    hipFuncSetAttribute((const void*)proj_gemm_kernel,
                        hipFuncAttributeMaxDynamicSharedMemorySize, 65536);
    attr_set = true;
  }

  cvt_all<<<2048, 256, 0, stream>>>(x, wqkv, wo, xb, wqkvb, wob);
  qkv_gemm_kernel<<<512, 512, 81920, stream>>>(xb, wqkvb, q_ws, k_ws, vt_ws, out);
  attn_kernel<<<32 * 32, 256, 0, stream>>>(q_ws, k_ws, vt_ws, o_ws);
  proj_gemm_kernel<<<256, 512, 65536, stream>>>(o_ws, wob, wo_b, out);
}